// Round 2
// baseline (3738.066 us; speedup 1.0000x reference)
//
#include <hip/hip_runtime.h>
#include <math.h>

#define BB 48
#define NN 96
#define EE 1024
#define DD 300
#define LL 4
#define G3 900          // 3*D
#define NC4 38          // weight chunks of 8 f16 (304 padded)
#define HDIM 3724       // D*(2L+1)+E
#define ROWS (BB*NN)    // 4608
#define NEGI -1.0e30f
#define KP300 304       // 300 padded to mult-of-8
#define GIC_TILES 540   // 15 x 36 tiles for fused GIc GEMM

typedef _Float16 half2_t __attribute__((ext_vector_type(2)));
typedef _Float16 h8 __attribute__((ext_vector_type(8)));
typedef float f4 __attribute__((ext_vector_type(4)));

__device__ __forceinline__ float sigm(float x){ return 1.0f/(1.0f+expf(-x)); }

__device__ __forceinline__ void dot4(const h8 wv, const h8 mc,
                                     float& a0, float& a1, float& a2, float& a3)
{
    half2_t w0,w1,w2,w3,m0,m1,m2,m3;
    w0.x=wv[0]; w0.y=wv[1]; m0.x=mc[0]; m0.y=mc[1];
    w1.x=wv[2]; w1.y=wv[3]; m1.x=mc[2]; m1.y=mc[3];
    w2.x=wv[4]; w2.y=wv[5]; m2.x=mc[4]; m2.y=mc[5];
    w3.x=wv[6]; w3.y=wv[7]; m3.x=mc[6]; m3.y=mc[7];
    a0 = __builtin_amdgcn_fdot2(w0, m0, a0, false);
    a1 = __builtin_amdgcn_fdot2(w1, m1, a1, false);
    a2 = __builtin_amdgcn_fdot2(w2, m2, a2, false);
    a3 = __builtin_amdgcn_fdot2(w3, m3, a3, false);
}

// ---------------- pack W (L,900,300) -> coalesced h8 chunks (L,38,900) ----------------
__global__ __launch_bounds__(256) void pack_w_q(const float* __restrict__ src_all,
                                                h8* __restrict__ dst)
{
    int l = blockIdx.y;
    int idx = blockIdx.x*256 + threadIdx.x;
    if (idx >= NC4*G3) return;
    int c = idx / G3, gate = idx % G3;
    const float* src = src_all + (size_t)l*G3*DD + (size_t)gate*DD;
    h8 v;
    #pragma unroll
    for (int j=0;j<8;j++){
        int d = 8*c + j;
        v[j] = (d<DD) ? (_Float16)src[d] : (_Float16)0.f;
    }
    dst[(size_t)l*NC4*G3 + idx] = v;
}

// ---------------- GRU weights [900][300] fp32 -> [900][304] f16 (zero-padded) ----------------
__global__ __launch_bounds__(256) void conv_gru_w(const float* __restrict__ gp_whh,
                                                  const float* __restrict__ gc_wih,
                                                  const float* __restrict__ gc_whh,
                                                  _Float16* __restrict__ outp)
{
    int z = blockIdx.y; int l = z/3, wsel = z%3;
    const float* src = (wsel==0?gp_whh:wsel==1?gc_wih:gc_whh) + (size_t)l*G3*DD;
    _Float16* dst = outp + (size_t)z*G3*KP300;
    int idx = blockIdx.x*256 + threadIdx.x;
    if (idx >= G3*KP300) return;
    int n = idx/KP300, k = idx%KP300;
    dst[idx] = (k<DD) ? (_Float16)src[(size_t)n*DD+k] : (_Float16)0.f;
}

// ---------------- transpose-convert [K][N] fp32 -> [N][Kpad] f16 ----------------
__global__ __launch_bounds__(256) void convT(const float* __restrict__ src,
                                             _Float16* __restrict__ dst,
                                             int K, int N, int Kpad)
{
    int idx = blockIdx.x*256 + threadIdx.x;
    if (idx >= N*Kpad) return;
    int n = idx/Kpad, k = idx%Kpad;
    dst[idx] = (k<K) ? (_Float16)src[(size_t)k*N + n] : (_Float16)0.f;
}

// ---------------- MFMA f16 GEMM tile body (device fn, 256 active threads) ----------------
__device__ __forceinline__ void gemm_tile(
    int m0, int n0, int tid,
    const float* __restrict__ A, int lda,
    const _Float16* __restrict__ B, int Kpad,
    const float* __restrict__ bias,
    float* __restrict__ C, int ldc,
    int N, int K, int relu)
{
    constexpr int KPS=40;
    __shared__ _Float16 As[128][KPS];
    __shared__ _Float16 Bs[64][KPS];
    int w = tid>>6, lane = tid&63;
    int wy = w>>1, wx = w&1;
    int lm = lane&15, q = lane>>4;

    f4 acc[4][2];
    #pragma unroll
    for (int a=0;a<4;a++)
        #pragma unroll
        for (int b=0;b<2;b++)
            #pragma unroll
            for (int r=0;r<4;r++) acc[a][b][r]=0.f;

    int am = tid>>1, akg = (tid&1)*16;
    int bn = tid>>2, bkg = (tid&3)*8;
    const float* arow = A + (size_t)(m0+am)*lda;

    for (int k0=0; k0<K; k0+=32){
        {
            __align__(16) _Float16 av[16];
            #pragma unroll
            for (int u=0;u<16;u+=4){
                int k = k0 + akg + u;
                float x0,x1,x2,x3;
                if (k+4 <= K){
                    float4 v = *(const float4*)(arow + k);
                    x0=v.x;x1=v.y;x2=v.z;x3=v.w;
                } else {
                    x0 = (k  <K)? arow[k  ]:0.f;
                    x1 = (k+1<K)? arow[k+1]:0.f;
                    x2 = (k+2<K)? arow[k+2]:0.f;
                    x3 = (k+3<K)? arow[k+3]:0.f;
                }
                av[u]=(_Float16)x0; av[u+1]=(_Float16)x1;
                av[u+2]=(_Float16)x2; av[u+3]=(_Float16)x3;
            }
            *(h8*)&As[am][akg]   = *(h8*)&av[0];
            *(h8*)&As[am][akg+8] = *(h8*)&av[8];
        }
        {
            int gk = k0 + bkg;
            h8 bv;
            #pragma unroll
            for (int j=0;j<8;j++) bv[j]=(_Float16)0.f;
            if (n0+bn < N && gk < Kpad)
                bv = *(const h8*)(B + (size_t)(n0+bn)*Kpad + gk);
            *(h8*)&Bs[bn][bkg] = bv;
        }
        __syncthreads();
        h8 af[4], bf[2];
        #pragma unroll
        for (int mb=0; mb<4; mb++) af[mb] = *(h8*)&As[wy*64+mb*16+lm][q*8];
        #pragma unroll
        for (int nb=0; nb<2; nb++) bf[nb] = *(h8*)&Bs[wx*32+nb*16+lm][q*8];
        #pragma unroll
        for (int mb=0; mb<4; mb++)
            #pragma unroll
            for (int nb=0; nb<2; nb++)
                acc[mb][nb] = __builtin_amdgcn_mfma_f32_16x16x32_f16(af[mb], bf[nb], acc[mb][nb], 0,0,0);
        __syncthreads();
    }
    #pragma unroll
    for (int mb=0; mb<4; mb++){
        int r0 = m0 + wy*64 + mb*16 + q*4;
        #pragma unroll
        for (int nb=0; nb<2; nb++){
            int c = n0 + wx*32 + nb*16 + lm;
            if (c < N){
                float bb = bias[c];
                #pragma unroll
                for (int reg=0; reg<4; reg++){
                    float v = acc[mb][nb][reg] + bb;
                    if (relu) v = fmaxf(v, 0.f);
                    C[(size_t)(r0+reg)*ldc + c] = v;
                }
            }
        }
    }
}

// ---------------- standalone MFMA GEMM kernel ----------------
__global__ __launch_bounds__(256) void gemm_mfma(
    const float* __restrict__ A, int lda,
    const _Float16* __restrict__ B, int Kpad,
    const float* __restrict__ bias,
    float* __restrict__ C, int ldc,
    int N, int K, int relu)
{
    gemm_tile(blockIdx.y*128, blockIdx.x*64, threadIdx.x,
              A, lda, B, Kpad, bias, C, ldc, N, K, relu);
}

// ---------------- copy features into last 1024 cols of Hbuf ----------------
__global__ void featcopy(const float* __restrict__ f, float* __restrict__ H)
{
    size_t row = blockIdx.x;
    int t = threadIdx.x;
    float4 v = *(const float4*)(f + row*EE + t*4);
    *(float4*)(H + row*HDIM + 2700 + t*4) = v;
}

// ---------------- fused scan + GIc GEMM ----------------
// blocks 0..47: sequential p-scan. K-transform: K_j = P_j@pwi^T + pbi (f16,
// bias baked in since softmax weights sum to 1); g_i = sum_j e_j*K_j.
// Phase A: K-matvec (18 asm-pinned resident chunks + 20 streamed) || softmax.
// Phase B: 2-way j-split f16 wsum (450+450 threads, half2 loads).
// Phase C: GRU || next-row prefetch. 3 barriers/step.
__global__ __launch_bounds__(1024, 4) void scan_kernel(
    float* __restrict__ Hbuf,
    const float* __restrict__ GHp,
    const h8* __restrict__ pwiQ,          // (38,900) h8 chunks of pwi
    const h8* __restrict__ pwhQ,          // (38,900) h8 chunks of pwh (init)
    const float* __restrict__ pbi,
    const float* __restrict__ pbh,
    const float* __restrict__ wk,
    const float* __restrict__ wq,
    const float* __restrict__ gat_b, int lidx,
    const float* __restrict__ adj,
    _Float16* __restrict__ Kh,            // f16 K rows: (ROWS, 900), pbi baked in
    float* __restrict__ Ebuf,             // f32 softmax rows: (ROWS, 96)
    int ccol, int hcol, int pcol,
    const _Float16* __restrict__ cwiF,
    const float* __restrict__ cbi,
    float* __restrict__ GIc)
{
    // ---- GEMM blocks ----
    if (blockIdx.x >= BB){
        if (threadIdx.x < 256){
            int bid = blockIdx.x - BB;
            int n0 = (bid % 15)*64, m0 = (bid / 15)*128;
            gemm_tile(m0, n0, threadIdx.x, Hbuf + ccol, HDIM, cwiF, KP300,
                      cbi, GIc, G3, G3, DD, 0);
        }
        return;
    }

    int b = blockIdx.x;
    int t = threadIdx.x;

    __shared__ __align__(16) float adj_s[NN*NN];      // 36864 B
    __shared__ __align__(16) float gpart[2][G3];      // 7200 B  (j-split partials)
    __shared__ __align__(16) float ghp_s[2][G3];      // 7200 B  (dbuf GHp row)
    __shared__ __align__(16) float hv_s[2][DD];       // 2400 B  (dbuf Hin row)
    __shared__ __align__(16) _Float16 cin_h[304];
    __shared__ __align__(16) _Float16 p_h[304];       // previous p row (f16)
    __shared__ float e_s[NN];
    __shared__ float pk_s[NN];
    __shared__ float qd_s[NN];
    __shared__ float pksum[8];

    size_t rowbase = (size_t)b*NN;

    // ---- one-time: 18 resident weight chunks, pinned via volatile asm
    h8 wr0,wr1,wr2,wr3,wr4,wr5,wr6,wr7,wr8,wr9,wr10,wr11,wr12,wr13,wr14,wr15,wr16,wr17;
    float pbi_r = 0.f, wk_r = 0.f;
    if (t < G3){
        const h8* W = pwiQ + t;
        wr0 = W[0];             wr1 = W[(size_t)1*G3];  wr2 = W[(size_t)2*G3];
        wr3 = W[(size_t)3*G3];  wr4 = W[(size_t)4*G3];  wr5 = W[(size_t)5*G3];
        wr6 = W[(size_t)6*G3];  wr7 = W[(size_t)7*G3];  wr8 = W[(size_t)8*G3];
        wr9 = W[(size_t)9*G3];  wr10 = W[(size_t)10*G3]; wr11 = W[(size_t)11*G3];
        wr12 = W[(size_t)12*G3]; wr13 = W[(size_t)13*G3]; wr14 = W[(size_t)14*G3];
        wr15 = W[(size_t)15*G3]; wr16 = W[(size_t)16*G3]; wr17 = W[(size_t)17*G3];
        pbi_r = pbi[t];
        // black-box: volatile asm can't be rematerialized -> values stay in VGPRs
        asm volatile("" : "+v"(wr0),"+v"(wr1),"+v"(wr2),"+v"(wr3),"+v"(wr4),
                          "+v"(wr5),"+v"(wr6),"+v"(wr7),"+v"(wr8));
        asm volatile("" : "+v"(wr9),"+v"(wr10),"+v"(wr11),"+v"(wr12),"+v"(wr13),
                          "+v"(wr14),"+v"(wr15),"+v"(wr16),"+v"(wr17));
    }
    if (t < DD) wk_r = wk[t];

    // ---- init A: adj staging + qdot + Cin0 staging + E row0 + row-1 prefetch
    for (int k=t; k<NN*NN; k+=1024) adj_s[k] = adj[rowbase*NN + k];
    {
        int w = t>>6, lane = t&63;
        float gb = gat_b[lidx];
        for (int r = w; r < NN; r += 16){
            const float* x = Hbuf + (rowbase + r)*HDIM + ccol;
            float s = 0.f;
            for (int d=lane; d<DD; d+=64) s += x[d]*wq[d];
            #pragma unroll
            for (int o=32;o>0;o>>=1) s += __shfl_xor(s,o);
            if (lane==0) qd_s[r] = s + gb;
        }
    }
    if (t < 150){
        float2 c2 = *(const float2*)&Hbuf[rowbase*HDIM + ccol + 2*t];
        cin_h[2*t]   = (_Float16)c2.x;
        cin_h[2*t+1] = (_Float16)c2.y;
    } else if (t < 152){
        cin_h[2*t]   = (_Float16)0.f;
        cin_h[2*t+1] = (_Float16)0.f;
    }
    if (t >= 256 && t < 352) Ebuf[rowbase*NN + (t-256)] = 0.f;
    if (t >= 512 && t < 812){
        int idx = t-512; size_t nrow = rowbase+1;
        if (idx < 225)
            *(float4*)&ghp_s[1][idx*4] = *(const float4*)&GHp[nrow*G3 + idx*4];
        else {
            int hh = idx-225;
            *(float4*)&hv_s[1][hh*4] = *(const float4*)&Hbuf[nrow*HDIM + hcol + hh*4];
        }
    }
    __syncthreads();
    // ---- init B: gh0 = Cin0 @ pwh^T + pbh
    if (t < G3){
        const h8* W2 = pwhQ + t;
        const h8* Cc = (const h8*)cin_h;
        float a0=0.f, a1=0.f, a2=0.f, a3=0.f;
        #pragma unroll 4
        for (int c=0;c<NC4;c++) dot4(W2[(size_t)c*G3], Cc[c], a0,a1,a2,a3);
        gpart[0][t] = pbh[t] + (a0+a2) + (a1+a3);
    }
    __syncthreads();
    // ---- init C: p0 = GRU(x=0, h=Cin0); pk partials; p_h pad
    if (t < 320){
        int d = t; float pw = 0.f;
        if (d < DD){
            float cin = Hbuf[rowbase*HDIM + ccol + d];
            float g0 = gpart[0][d], g1 = gpart[0][DD+d], g2 = gpart[0][2*DD+d];
            float r = sigm(pbi[d]        + g0);
            float z = sigm(pbi[DD+d]     + g1);
            float n = tanhf(pbi[2*DD+d]  + r*g2);
            float p = (1.f-z)*n + z*cin;
            Hbuf[rowbase*HDIM + pcol + d] = p;
            p_h[d] = (_Float16)p;
            pw = p * wk_r;
        } else if (d < 304){
            p_h[d] = (_Float16)0.f;
        }
        #pragma unroll
        for (int o=32;o>0;o>>=1) pw += __shfl_xor(pw,o);
        if ((t&63)==0) pksum[t>>6] = pw;
    }
    __syncthreads();

    for (int i=1;i<NN;i++){
        size_t row = rowbase + i;
        // ---- phase A: K[i-1] = p_h @ pwi^T + pbi -> f16 (t<900) || softmax (t>=960)
        if (t < G3){
            const h8* W  = pwiQ + t;
            const h8* Pr = (const h8*)p_h;
            float a0=0.f, a1=0.f, a2=0.f, a3=0.f;
            dot4(wr0,  Pr[0],  a0,a1,a2,a3);
            dot4(wr1,  Pr[1],  a0,a1,a2,a3);
            dot4(wr2,  Pr[2],  a0,a1,a2,a3);
            dot4(wr3,  Pr[3],  a0,a1,a2,a3);
            dot4(wr4,  Pr[4],  a0,a1,a2,a3);
            dot4(wr5,  Pr[5],  a0,a1,a2,a3);
            dot4(wr6,  Pr[6],  a0,a1,a2,a3);
            dot4(wr7,  Pr[7],  a0,a1,a2,a3);
            dot4(wr8,  Pr[8],  a0,a1,a2,a3);
            dot4(wr9,  Pr[9],  a0,a1,a2,a3);
            dot4(wr10, Pr[10], a0,a1,a2,a3);
            dot4(wr11, Pr[11], a0,a1,a2,a3);
            dot4(wr12, Pr[12], a0,a1,a2,a3);
            dot4(wr13, Pr[13], a0,a1,a2,a3);
            dot4(wr14, Pr[14], a0,a1,a2,a3);
            dot4(wr15, Pr[15], a0,a1,a2,a3);
            dot4(wr16, Pr[16], a0,a1,a2,a3);
            dot4(wr17, Pr[17], a0,a1,a2,a3);
            #pragma unroll 4
            for (int c=18;c<NC4;c++){
                dot4(W[(size_t)c*G3], Pr[c], a0,a1,a2,a3);
            }
            float kv = (a0+a2) + (a1+a3) + pbi_r;
            Kh[(row-1)*G3 + t] = (_Float16)kv;
        } else if (t >= 960){
            int lane = t - 960;
            float s_last = pksum[0]+pksum[1]+pksum[2]+pksum[3]+pksum[4];
            if (lane==0) pk_s[i-1] = s_last;
            float q = qd_s[i];
            float a0 = NEGI, a1 = NEGI;
            if (lane < i && adj_s[i*NN+lane] != 0.f)
                a0 = q + ((lane==i-1)? s_last : pk_s[lane]);
            int j1 = 64+lane;
            if (lane < 32 && j1 < i && adj_s[i*NN+j1] != 0.f)
                a1 = q + ((j1==i-1)? s_last : pk_s[j1]);
            float m = fmaxf(a0,a1);
            #pragma unroll
            for (int o=32;o>0;o>>=1) m = fmaxf(m, __shfl_xor(m,o));
            float e0 = expf(a0-m);
            float e1 = (lane<32)? expf(a1-m) : 0.f;
            float ss = e0+e1;
            #pragma unroll
            for (int o=32;o>0;o>>=1) ss += __shfl_xor(ss,o);
            float inv = 1.f/ss;
            e_s[lane] = e0*inv;
            if (lane<32) e_s[64+lane] = e1*inv;
        }
        __syncthreads();
        // ---- phase B: g partials = sum_j e_j*K_j, 2-way j-split || E-row store
        if (t < G3){
            int grp = (t >= 450);
            int tt  = grp ? t-450 : t;
            int d2  = 2*tt;
            int j0  = grp ? (i>>1) : 0;
            int j1  = grp ? i : (i>>1);
            const _Float16* Kr = Kh + rowbase*G3 + d2;
            float m0 = 0.f, m1 = 0.f;
            #pragma unroll 8
            for (int j=j0;j<j1;j++){
                float w = e_s[j];
                half2_t kv = *(const half2_t*)(Kr + (size_t)j*G3);
                m0 = fmaf(w, (float)kv.x, m0);
                m1 = fmaf(w, (float)kv.y, m1);
            }
            *(float2*)&gpart[grp][d2] = make_float2(m0,m1);
        } else if (t < 996){
            Ebuf[row*NN + (t-900)] = e_s[t-900];
        }
        __syncthreads();
        // ---- phase C: GRU (t<320) || prefetch ghp/hv row i+1 (t 384..683)
        if (t < 320){
            int d = t; float pw = 0.f;
            int buf = i&1;
            if (d < DD){
                float g0 = gpart[0][d]      + gpart[1][d];
                float g1 = gpart[0][DD+d]   + gpart[1][DD+d];
                float g2 = gpart[0][2*DD+d] + gpart[1][2*DD+d];
                float r = sigm(g0           + ghp_s[buf][d]);
                float z = sigm(g1           + ghp_s[buf][DD+d]);
                float n = tanhf(g2          + r*ghp_s[buf][2*DD+d]);
                float p = (1.f-z)*n + z*hv_s[buf][d];
                Hbuf[row*HDIM + pcol + d] = p;
                p_h[d] = (_Float16)p;
                pw = p * wk_r;
            }
            #pragma unroll
            for (int o=32;o>0;o>>=1) pw += __shfl_xor(pw,o);
            if ((t&63)==0) pksum[t>>6] = pw;
        } else if (t >= 384 && t < 684 && i < NN-1){
            int idx = t-384; size_t nrow = row+1;
            int buf = (i+1)&1;
            if (idx < 225)
                *(float4*)&ghp_s[buf][idx*4] = *(const float4*)&GHp[nrow*G3 + idx*4];
            else {
                int hh = idx-225;
                *(float4*)&hv_s[buf][hh*4] = *(const float4*)&Hbuf[nrow*HDIM + hcol + hh*4];
            }
        }
        __syncthreads();
    }
}

// ---------------- M = E * P  (per batch: 96x96 @ 96x300), 16 i-rows per block ----------------
__global__ __launch_bounds__(320) void m_gemm(
    const float* __restrict__ Ebuf, const float* __restrict__ Hbuf,
    float* __restrict__ Mbuf, int pcol)
{
    int b = blockIdx.y, it = blockIdx.x;
    __shared__ float Es[16][96];
    int t = threadIdx.x;
    size_t rowbase = (size_t)b*NN;
    for (int k=t; k<16*96; k+=320){
        int r = k/96, j = k%96;
        Es[r][j] = Ebuf[(rowbase + it*16 + r)*NN + j];
    }
    __syncthreads();
    if (t < DD){
        float acc[16];
        #pragma unroll
        for (int r=0;r<16;r++) acc[r] = 0.f;
        int jmax = it*16 + 16; if (jmax > NN) jmax = NN;  // E[i][j]=0 for j>=i
        for (int j=0;j<jmax;j++){
            float p = Hbuf[(rowbase+j)*HDIM + pcol + t];
            #pragma unroll
            for (int r=0;r<16;r++) acc[r] = fmaf(Es[r][j], p, acc[r]);
        }
        #pragma unroll
        for (int r=0;r<16;r++)
            Mbuf[(rowbase + it*16 + r)*DD + t] = acc[r];
    }
}

// ---------------- c-side elementwise combine ----------------
__global__ __launch_bounds__(320) void combine_c(
    const float* __restrict__ GIc, const float* __restrict__ GHc,
    const float* __restrict__ Mbuf, float* __restrict__ Hbuf, int clcol)
{
    size_t row = blockIdx.x;
    int d = threadIdx.x;
    if (d < DD){
        float ir = GIc[row*G3+d], iz = GIc[row*G3+DD+d], inn = GIc[row*G3+2*DD+d];
        float hr = GHc[row*G3+d], hz = GHc[row*G3+DD+d], hn  = GHc[row*G3+2*DD+d];
        float r  = sigm(ir+hr);
        float z  = sigm(iz+hz);
        float nn = tanhf(inn + r*hn);
        float h  = Mbuf[row*DD+d];
        Hbuf[row*HDIM + clcol + d] = (1.f-z)*nn + z*h;
    }
}

// ---------------- logits: out = x2 @ w2 + b2 (N=7) ----------------
__global__ __launch_bounds__(64) void logits_kernel(
    const float* __restrict__ x2, const float* __restrict__ w2,
    const float* __restrict__ b2, float* __restrict__ out)
{
    size_t row = blockIdx.x;
    int lane = threadIdx.x;
    float acc[7]={0,0,0,0,0,0,0};
    for (int d=lane; d<DD; d+=64){
        float x = x2[row*DD+d];
        #pragma unroll
        for (int c=0;c<7;c++) acc[c] += x*w2[d*7+c];
    }
    #pragma unroll
    for (int c=0;c<7;c++){
        float s = acc[c];
        #pragma unroll
        for (int o=32;o>0;o>>=1) s += __shfl_down(s,o);
        if (lane==0) out[row*7+c] = s + b2[c];
    }
}

extern "C" void kernel_launch(void* const* d_in, const int* in_sizes, int n_in,
                              void* d_out, int out_size, void* d_ws, size_t ws_size,
                              hipStream_t stream)
{
    const float* features = (const float*)d_in[0];
    const float* adj      = (const float*)d_in[1];
    const float* fc1_w    = (const float*)d_in[3];
    const float* fc1_b    = (const float*)d_in[4];
    const float* gc_wih   = (const float*)d_in[5];
    const float* gc_whh   = (const float*)d_in[6];
    const float* gc_bih   = (const float*)d_in[7];
    const float* gc_bhh   = (const float*)d_in[8];
    const float* gp_wih   = (const float*)d_in[9];
    const float* gp_whh   = (const float*)d_in[10];
    const float* gp_bih   = (const float*)d_in[11];
    const float* gp_bhh   = (const float*)d_in[12];
    const float* gat_wq   = (const float*)d_in[13];
    const float* gat_wk   = (const float*)d_in[14];
    const float* gat_b    = (const float*)d_in[15];
    const float* mlp_w0   = (const float*)d_in[16];
    const float* mlp_b0   = (const float*)d_in[17];
    const float* mlp_w1   = (const float*)d_in[18];
    const float* mlp_b1   = (const float*)d_in[19];
    const float* mlp_w2   = (const float*)d_in[20];
    const float* mlp_b2   = (const float*)d_in[21];
    float* out = (float*)d_out;

    float* ws = (float*)d_ws;
    size_t off = 0;
    float* Hbuf = ws + off; off += (size_t)ROWS*HDIM;
    float* bufA = ws + off; off += (size_t)ROWS*G3;    // GHp
    float* bufB = ws + off; off += (size_t)ROWS*G3;    // GIc / x1
    float* bufC = ws + off; off += (size_t)ROWS*G3;    // Kh (scan, f16) -> GHc / x2
    float* Mbuf = ws + off; off += (size_t)ROWS*DD;
    h8* pwiQ = (h8*)(ws + off); off += (size_t)LL*NC4*G3*4;
    h8* pwhQ = (h8*)(ws + off); off += (size_t)LL*NC4*G3*4;
    _Float16* gruF = (_Float16*)(ws + off); off += (size_t)12*G3*KP300/2;
    _Float16* fc1F = (_Float16*)(ws + off); off += (size_t)DD*EE/2;
    _Float16* mlp0F= (_Float16*)(ws + off); off += (size_t)DD*3728/2;
    _Float16* mlp1F= (_Float16*)(ws + off); off += (size_t)DD*KP300/2;
    float* Ebuf = ws + off; off += (size_t)ROWS*NN;    // softmax rows
    (void)ws_size; (void)in_sizes; (void)n_in; (void)out_size;

    // 1. weight prep
    {
        pack_w_q<<<dim3((NC4*G3+255)/256, LL), 256, 0, stream>>>(gp_wih, pwiQ);
        pack_w_q<<<dim3((NC4*G3+255)/256, LL), 256, 0, stream>>>(gp_whh, pwhQ);
        conv_gru_w<<<dim3((G3*KP300+255)/256, 12), 256, 0, stream>>>(gp_whh, gc_wih, gc_whh, gruF);
        convT<<<(DD*EE+255)/256, 256, 0, stream>>>(fc1_w, fc1F, EE, DD, EE);
        convT<<<(DD*3728+255)/256, 256, 0, stream>>>(mlp_w0, mlp0F, HDIM, DD, 3728);
        convT<<<(DD*KP300+255)/256, 256, 0, stream>>>(mlp_w1, mlp1F, DD, DD, KP300);
    }
    // 2. H0 = relu(features @ fc1_w + fc1_b) -> Hbuf col 0
    gemm_mfma<<<dim3(5,36),256,0,stream>>>(features, EE, fc1F, EE, fc1_b,
                                           Hbuf, HDIM, DD, EE, 1);
    // 3. features -> Hbuf cols [2700,3724)
    featcopy<<<ROWS,256,0,stream>>>(features, Hbuf);

    for (int l=0;l<LL;l++){
        int ccol  = (l==0)? 0 : 300 + (l-1)*600;
        int hcol  = l*300;
        int pcol  = 600 + l*600;
        int clcol = 300 + l*600;
        const h8* pwiQl = pwiQ + (size_t)l*NC4*G3;
        const h8* pwhQl = pwhQ + (size_t)l*NC4*G3;
        const _Float16* pwhF = gruF + (size_t)(l*3+0)*G3*KP300;
        const _Float16* cwiF = gruF + (size_t)(l*3+1)*G3*KP300;
        const _Float16* cwhF = gruF + (size_t)(l*3+2)*G3*KP300;

        // GHp = Hin @ pwh^T + pbh
        gemm_mfma<<<dim3(15,36),256,0,stream>>>(Hbuf+hcol, HDIM, pwhF, KP300,
                                                gp_bhh + l*G3, bufA, G3, G3, DD, 0);
        // fused: scan (blocks 0..47, K-transform) + GIc GEMM (blocks 48..587)
        // Kh scratch aliases bufC (dead until GHc GEMM below, stream-ordered).
        scan_kernel<<<BB+GIC_TILES,1024,0,stream>>>(Hbuf, bufA, pwiQl, pwhQl,
                                          gp_bih + l*G3, gp_bhh + l*G3,
                                          gat_wk + l*DD, gat_wq + l*DD, gat_b, l,
                                          adj, (_Float16*)bufC, Ebuf, ccol, hcol, pcol,
                                          cwiF, gc_bih + l*G3, bufB);
        // M = E * P (off the scan critical path)
        m_gemm<<<dim3(6,BB),320,0,stream>>>(Ebuf, Hbuf, Mbuf, pcol);
        // GHc = M @ cwh^T + cbh
        gemm_mfma<<<dim3(15,36),256,0,stream>>>(Mbuf, DD, cwhF, KP300,
                                                gc_bhh + l*G3, bufC, G3, G3, DD, 0);
        // CL = GRU-combine
        combine_c<<<ROWS,320,0,stream>>>(bufB, bufC, Mbuf, Hbuf, clcol);
    }

    // MLP
    gemm_mfma<<<dim3(5,36),256,0,stream>>>(Hbuf, HDIM, mlp0F, 3728, mlp_b0,
                                           bufB, DD, DD, HDIM, 1);
    gemm_mfma<<<dim3(5,36),256,0,stream>>>(bufB, DD, mlp1F, KP300, mlp_b1,
                                           bufC, DD, DD, DD, 1);
    logits_kernel<<<ROWS,64,0,stream>>>(bufC, mlp_w2, mlp_b2, out);
}

// Round 3
// 3103.138 us; speedup vs baseline: 1.2046x; 1.2046x over previous
//
#include <hip/hip_runtime.h>
#include <math.h>

#define BB 48
#define NN 96
#define EE 1024
#define DD 300
#define LL 4
#define G3 900          // 3*D
#define PP 150          // DD/2 f16 pairs
#define PP2 152         // padded pairs (38 chunks of 4)
#define NC4 38          // weight chunks of 4 pairs
#define HDIM 3724       // D*(2L+1)+E
#define ROWS (BB*NN)    // 4608
#define NEGI -1.0e30f
#define KP300 304       // 300 padded to mult-of-8
#define GIC_TILES 540   // 15 x 36 tiles for fused GIc GEMM

#define NREG 14         // pwi chunks pinned in VGPRs (56 regs, fits 128 budget)
#define NLDS 5          // pwi chunks resident in LDS (72000 B)
// streamed chunks: NC4 - NREG - NLDS = 19

typedef _Float16 half2_t __attribute__((ext_vector_type(2)));
typedef _Float16 h8 __attribute__((ext_vector_type(8)));
typedef float f4 __attribute__((ext_vector_type(4)));

__device__ __forceinline__ float sigm(float x){ return 1.0f/(1.0f+expf(-x)); }

__device__ __forceinline__ void dot4(const h8 wv, const h8 mc,
                                     float& a0, float& a1, float& a2, float& a3)
{
    half2_t w0,w1,w2,w3,m0,m1,m2,m3;
    w0.x=wv[0]; w0.y=wv[1]; m0.x=mc[0]; m0.y=mc[1];
    w1.x=wv[2]; w1.y=wv[3]; m1.x=mc[2]; m1.y=mc[3];
    w2.x=wv[4]; w2.y=wv[5]; m2.x=mc[4]; m2.y=mc[5];
    w3.x=wv[6]; w3.y=wv[7]; m3.x=mc[6]; m3.y=mc[7];
    a0 = __builtin_amdgcn_fdot2(w0, m0, a0, false);
    a1 = __builtin_amdgcn_fdot2(w1, m1, a1, false);
    a2 = __builtin_amdgcn_fdot2(w2, m2, a2, false);
    a3 = __builtin_amdgcn_fdot2(w3, m3, a3, false);
}

// ---------------- pack W (L,900,300) -> coalesced h8 chunks (L,38,900) ----------------
__global__ __launch_bounds__(256) void pack_w_q(const float* __restrict__ src_all,
                                                h8* __restrict__ dst)
{
    int l = blockIdx.y;
    int idx = blockIdx.x*256 + threadIdx.x;
    if (idx >= NC4*G3) return;
    int c = idx / G3, gate = idx % G3;
    const float* src = src_all + (size_t)l*G3*DD + (size_t)gate*DD;
    h8 v;
    #pragma unroll
    for (int j=0;j<8;j++){
        int d = 8*c + j;
        v[j] = (d<DD) ? (_Float16)src[d] : (_Float16)0.f;
    }
    dst[(size_t)l*NC4*G3 + idx] = v;
}

// ---------------- GRU weights [900][300] fp32 -> [900][304] f16 (zero-padded) ----------------
__global__ __launch_bounds__(256) void conv_gru_w(const float* __restrict__ gp_whh,
                                                  const float* __restrict__ gc_wih,
                                                  const float* __restrict__ gc_whh,
                                                  _Float16* __restrict__ outp)
{
    int z = blockIdx.y; int l = z/3, wsel = z%3;
    const float* src = (wsel==0?gp_whh:wsel==1?gc_wih:gc_whh) + (size_t)l*G3*DD;
    _Float16* dst = outp + (size_t)z*G3*KP300;
    int idx = blockIdx.x*256 + threadIdx.x;
    if (idx >= G3*KP300) return;
    int n = idx/KP300, k = idx%KP300;
    dst[idx] = (k<DD) ? (_Float16)src[(size_t)n*DD+k] : (_Float16)0.f;
}

// ---------------- transpose-convert [K][N] fp32 -> [N][Kpad] f16 ----------------
__global__ __launch_bounds__(256) void convT(const float* __restrict__ src,
                                             _Float16* __restrict__ dst,
                                             int K, int N, int Kpad)
{
    int idx = blockIdx.x*256 + threadIdx.x;
    if (idx >= N*Kpad) return;
    int n = idx/Kpad, k = idx%Kpad;
    dst[idx] = (k<K) ? (_Float16)src[(size_t)k*N + n] : (_Float16)0.f;
}

// ---------------- MFMA f16 GEMM tile body (device fn, 256 active threads) ----------------
__device__ __forceinline__ void gemm_tile(
    int m0, int n0, int tid,
    const float* __restrict__ A, int lda,
    const _Float16* __restrict__ B, int Kpad,
    const float* __restrict__ bias,
    float* __restrict__ C, int ldc,
    int N, int K, int relu,
    _Float16 (*As)[40], _Float16 (*Bs)[40])
{
    int w = tid>>6, lane = tid&63;
    int wy = w>>1, wx = w&1;
    int lm = lane&15, q = lane>>4;

    f4 acc[4][2];
    #pragma unroll
    for (int a=0;a<4;a++)
        #pragma unroll
        for (int b=0;b<2;b++)
            #pragma unroll
            for (int r=0;r<4;r++) acc[a][b][r]=0.f;

    int am = tid>>1, akg = (tid&1)*16;
    int bn = tid>>2, bkg = (tid&3)*8;
    const float* arow = A + (size_t)(m0+am)*lda;

    for (int k0=0; k0<K; k0+=32){
        {
            __align__(16) _Float16 av[16];
            #pragma unroll
            for (int u=0;u<16;u+=4){
                int k = k0 + akg + u;
                float x0,x1,x2,x3;
                if (k+4 <= K){
                    float4 v = *(const float4*)(arow + k);
                    x0=v.x;x1=v.y;x2=v.z;x3=v.w;
                } else {
                    x0 = (k  <K)? arow[k  ]:0.f;
                    x1 = (k+1<K)? arow[k+1]:0.f;
                    x2 = (k+2<K)? arow[k+2]:0.f;
                    x3 = (k+3<K)? arow[k+3]:0.f;
                }
                av[u]=(_Float16)x0; av[u+1]=(_Float16)x1;
                av[u+2]=(_Float16)x2; av[u+3]=(_Float16)x3;
            }
            *(h8*)&As[am][akg]   = *(h8*)&av[0];
            *(h8*)&As[am][akg+8] = *(h8*)&av[8];
        }
        {
            int gk = k0 + bkg;
            h8 bv;
            #pragma unroll
            for (int j=0;j<8;j++) bv[j]=(_Float16)0.f;
            if (n0+bn < N && gk < Kpad)
                bv = *(const h8*)(B + (size_t)(n0+bn)*Kpad + gk);
            *(h8*)&Bs[bn][bkg] = bv;
        }
        __syncthreads();
        h8 af[4], bf[2];
        #pragma unroll
        for (int mb=0; mb<4; mb++) af[mb] = *(h8*)&As[wy*64+mb*16+lm][q*8];
        #pragma unroll
        for (int nb=0; nb<2; nb++) bf[nb] = *(h8*)&Bs[wx*32+nb*16+lm][q*8];
        #pragma unroll
        for (int mb=0; mb<4; mb++)
            #pragma unroll
            for (int nb=0; nb<2; nb++)
                acc[mb][nb] = __builtin_amdgcn_mfma_f32_16x16x32_f16(af[mb], bf[nb], acc[mb][nb], 0,0,0);
        __syncthreads();
    }
    #pragma unroll
    for (int mb=0; mb<4; mb++){
        int r0 = m0 + wy*64 + mb*16 + q*4;
        #pragma unroll
        for (int nb=0; nb<2; nb++){
            int c = n0 + wx*32 + nb*16 + lm;
            if (c < N){
                float bb = bias[c];
                #pragma unroll
                for (int reg=0; reg<4; reg++){
                    float v = acc[mb][nb][reg] + bb;
                    if (relu) v = fmaxf(v, 0.f);
                    C[(size_t)(r0+reg)*ldc + c] = v;
                }
            }
        }
    }
}

// ---------------- standalone MFMA GEMM kernel ----------------
__global__ __launch_bounds__(256) void gemm_mfma(
    const float* __restrict__ A, int lda,
    const _Float16* __restrict__ B, int Kpad,
    const float* __restrict__ bias,
    float* __restrict__ C, int ldc,
    int N, int K, int relu)
{
    __shared__ _Float16 As[128][40];
    __shared__ _Float16 Bs[64][40];
    gemm_tile(blockIdx.y*128, blockIdx.x*64, threadIdx.x,
              A, lda, B, Kpad, bias, C, ldc, N, K, relu, As, Bs);
}

// ---------------- copy features into last 1024 cols of Hbuf ----------------
__global__ void featcopy(const float* __restrict__ f, float* __restrict__ H)
{
    size_t row = blockIdx.x;
    int t = threadIdx.x;
    float4 v = *(const float4*)(f + row*EE + t*4);
    *(float4*)(H + row*HDIM + 2700 + t*4) = v;
}

// ---------------- fused scan + GIc GEMM ----------------
// blocks 0..47: sequential p-scan. blocks 48..587: GIc GEMM tiles.
// Round-0 5-phase structure. Phase-D weight supply: 14 chunks pinned in VGPRs
// (volatile-asm black-box -> cannot be rematerialized or spilled within 128-reg
// budget), 5 chunks resident in LDS (loaded once), 19 streamed from L2.
// adj stored as LDS bitmask (1.5 KB vs 36.9 KB) to make room for LDS weights.
__global__ __launch_bounds__(1024, 4) void scan_kernel(
    float* __restrict__ Hbuf,
    const float* __restrict__ GHp,
    const h8* __restrict__ pwiQ,          // (38,900) h8 chunks of pwi
    const h8* __restrict__ pwhQ,          // (38,900) h8 chunks of pwh (init)
    const float* __restrict__ pbi,
    const float* __restrict__ pbh,
    const float* __restrict__ wk,
    const float* __restrict__ wq,
    const float* __restrict__ gat_b, int lidx,
    const float* __restrict__ adj,
    float* __restrict__ Mbuf,
    int ccol, int hcol, int pcol,
    const _Float16* __restrict__ cwiF,
    const float* __restrict__ cbi,
    float* __restrict__ GIc)
{
    __shared__ __align__(16) char pool[146432];

    // ---- GEMM blocks (LDS pool reused as As/Bs) ----
    if (blockIdx.x >= BB){
        if (threadIdx.x < 256){
            _Float16 (*As)[40] = (_Float16 (*)[40])pool;
            _Float16 (*Bs)[40] = (_Float16 (*)[40])(pool + 128*40*2);
            int bid = blockIdx.x - BB;
            int n0 = (bid % 15)*64, m0 = (bid / 15)*128;
            gemm_tile(m0, n0, threadIdx.x, Hbuf + ccol, HDIM, cwiF, KP300,
                      cbi, GIc, G3, G3, DD, 0, As, Bs);
        }
        return;
    }

    int b = blockIdx.x;
    int t = threadIdx.x;

    // ---- LDS pool carve-up (all offsets 16B aligned) ----
    half2_t (*P_h2)[PP]   = (half2_t (*)[PP])(pool);             //  57600
    h8*      Wlds         = (h8*)(pool + 57600);                 //  72000 (5 chunks)
    float*   g_s          = (float*)(pool + 129600);             //   3600
    float  (*Mpart)[DD]   = (float (*)[DD])(pool + 133200);      //   3600
    float*   ghp_s        = (float*)(pool + 136800);             //   3600
    float*   hv_s         = (float*)(pool + 140400);             //   1200
    float*   pw_s         = (float*)(pool + 141600);             //   1200
    half2_t* M_h2         = (half2_t*)(pool + 142800);           //    608
    float*   e_s          = (float*)(pool + 143424);             //    384
    float*   pk_s         = (float*)(pool + 143808);             //    384
    float*   qd_s         = (float*)(pool + 144192);             //    384
    unsigned (*adjb)[4]   = (unsigned (*)[4])(pool + 144576);    //   1536 -> 146112

    size_t rowbase = (size_t)b*NN;

    // ---- one-time: 14 pinned weight chunks + per-thread constants
    h8 wr0,wr1,wr2,wr3,wr4,wr5,wr6,wr7,wr8,wr9,wr10,wr11,wr12,wr13;
    float pbi_r = 0.f;
    if (t < G3){
        const h8* W = pwiQ + t;
        wr0 = W[0];             wr1 = W[(size_t)1*G3];  wr2 = W[(size_t)2*G3];
        wr3 = W[(size_t)3*G3];  wr4 = W[(size_t)4*G3];  wr5 = W[(size_t)5*G3];
        wr6 = W[(size_t)6*G3];  wr7 = W[(size_t)7*G3];  wr8 = W[(size_t)8*G3];
        wr9 = W[(size_t)9*G3];  wr10 = W[(size_t)10*G3]; wr11 = W[(size_t)11*G3];
        wr12 = W[(size_t)12*G3]; wr13 = W[(size_t)13*G3];
        pbi_r = pbi[t];
        // opaque transform: values can no longer be rematerialized from loads
        asm volatile("" : "+v"(wr0),"+v"(wr1),"+v"(wr2),"+v"(wr3),
                          "+v"(wr4),"+v"(wr5),"+v"(wr6));
        asm volatile("" : "+v"(wr7),"+v"(wr8),"+v"(wr9),"+v"(wr10),
                          "+v"(wr11),"+v"(wr12),"+v"(wr13));
    }
    float2 wk_r = make_float2(0.f,0.f);
    if (t < PP) wk_r = *(const float2*)&wk[2*t];

    // ---- init phase 1: LDS weight chunks + adj bitmask + qdot + Cin0 -> M
    for (int idx=t; idx<NLDS*G3; idx+=1024)
        Wlds[idx] = pwiQ[(size_t)(NREG + idx/G3)*G3 + (idx%G3)];
    if (t < NN*3){
        int r = t/3, w = t%3;
        const float* arow = adj + (rowbase + r)*NN + w*32;
        unsigned m = 0;
        for (int c=0;c<32;c++) if (arow[c] != 0.f) m |= (1u<<c);
        adjb[r][w] = m;
    }
    {
        int w = t>>6, lane = t&63;
        float gb = gat_b[lidx];
        for (int r = w; r < NN; r += 16){
            const float* x = Hbuf + (rowbase + r)*HDIM + ccol;
            float s = 0.f;
            for (int d=lane; d<DD; d+=64) s += x[d]*wq[d];
            #pragma unroll
            for (int o=32;o>0;o>>=1) s += __shfl_xor(s,o);
            if (lane==0) qd_s[r] = s + gb;
        }
    }
    if (t < PP){
        float2 c2 = *(const float2*)&Hbuf[rowbase*HDIM + ccol + 2*t];
        Mpart[0][2*t] = c2.x; Mpart[0][2*t+1] = c2.y;
        half2_t mh; mh.x = (_Float16)c2.x; mh.y = (_Float16)c2.y;
        M_h2[t] = mh;
    } else if (t < PP2){
        half2_t z; z.x=(_Float16)0.f; z.y=(_Float16)0.f;
        M_h2[t] = z;
    }
    __syncthreads();
    // ---- init phase 2: gh0 = Cin0 @ pwh^T + pbh
    if (t < G3){
        const h8* W2 = pwhQ + t;
        float a0=0.f, a1=0.f, a2=0.f, a3=0.f;
        #pragma unroll 4
        for (int c=0;c<NC4;c++){
            h8 wv = W2[(size_t)c*G3];
            h8 mc = *(h8*)&M_h2[4*c];
            dot4(wv, mc, a0,a1,a2,a3);
        }
        g_s[t] = pbh[t] + (a0+a2) + (a1+a3);
    }
    __syncthreads();
    // ---- init phase 3: p0 = GRU(x=0, h=Cin0); M[b,0]=0
    if (t < PP){
        int d0 = 2*t, d1 = 2*t+1;
        float r0  = sigm(pbi[d0]      + g_s[d0]);
        float z0  = sigm(pbi[DD+d0]   + g_s[DD+d0]);
        float n0  = tanhf(pbi[2*DD+d0] + r0*g_s[2*DD+d0]);
        float p0  = (1.f-z0)*n0 + z0*Mpart[0][d0];
        float r1  = sigm(pbi[d1]      + g_s[d1]);
        float z1  = sigm(pbi[DD+d1]   + g_s[DD+d1]);
        float n1  = tanhf(pbi[2*DD+d1] + r1*g_s[2*DD+d1]);
        float p1  = (1.f-z1)*n1 + z1*Mpart[0][d1];
        *(float2*)&Hbuf[rowbase*HDIM + pcol + d0] = make_float2(p0,p1);
        half2_t ph; ph.x = (_Float16)p0; ph.y = (_Float16)p1;
        P_h2[0][t] = ph;
        pw_s[d0] = p0*wk_r.x;
        pw_s[d1] = p1*wk_r.y;
        *(float2*)&Mbuf[rowbase*DD + d0] = make_float2(0.f,0.f);
    }
    __syncthreads();

    for (int i=1;i<NN;i++){
        size_t row = rowbase + i;
        // ---- AB (wave 0): pk reduce + logits + softmax (adj via bitmask)
        if (t < 64){
            float s = 0.f;
            for (int c=t;c<DD;c+=64) s += pw_s[c];
            #pragma unroll
            for (int o=32;o>0;o>>=1) s += __shfl_xor(s,o);
            if (t==0) pk_s[i-1] = s;
            float q = qd_s[i];
            float a0 = NEGI, a1 = NEGI;
            if (t < i){
                if ((adjb[i][t>>5]>>(t&31))&1u) a0 = q + ((t==i-1)? s : pk_s[t]);
            }
            int j1 = 64+t;
            if (t < 32 && j1 < i){
                if ((adjb[i][2]>>t)&1u) a1 = q + ((j1==i-1)? s : pk_s[j1]);
            }
            float m = fmaxf(a0,a1);
            #pragma unroll
            for (int o=32;o>0;o>>=1) m = fmaxf(m, __shfl_xor(m,o));
            float e0 = expf(a0-m);
            float e1 = (t<32)? expf(a1-m) : 0.f;
            float ss = e0+e1;
            #pragma unroll
            for (int o=32;o>0;o>>=1) ss += __shfl_xor(ss,o);
            float inv = 1.f/ss;
            e_s[t] = e0*inv;
            if (t<32) e_s[64+t] = e1*inv;
        }
        __syncthreads();
        // ---- C (t<450): 3-way j-split weighted sum; prefetchers (t>=512)
        if (t < 450){
            int g = t/150, dp = t%150;
            int cnt = (i+2)/3;
            int j0 = g*cnt; int j1 = j0+cnt; if (j1 > i) j1 = i;
            float m0=0.f, m1=0.f;
            for (int j=j0;j<j1;j++){
                float w = e_s[j];
                half2_t pv = P_h2[j][dp];
                m0 += w*(float)pv.x;
                m1 += w*(float)pv.y;
            }
            *(float2*)&Mpart[g][2*dp] = make_float2(m0,m1);
        } else if (t >= 512){
            int k = t-512;
            #pragma unroll
            for (int it=0; it<2; it++){
                int idx = k + it*512;
                if (idx < 450){
                    *(float2*)&ghp_s[2*idx] = *(const float2*)&GHp[row*G3 + 2*idx];
                } else if (idx < 600){
                    int h = idx-450;
                    *(float2*)&hv_s[2*h] = *(const float2*)&Hbuf[row*HDIM + hcol + 2*h];
                }
            }
        }
        __syncthreads();
        // ---- Csum (t<150): combine partials, write Mbuf + f16 M
        if (t < PP){
            float m0 = Mpart[0][2*t] + Mpart[1][2*t] + Mpart[2][2*t];
            float m1 = Mpart[0][2*t+1] + Mpart[1][2*t+1] + Mpart[2][2*t+1];
            half2_t mh; mh.x = (_Float16)m0; mh.y = (_Float16)m1;
            M_h2[t] = mh;
            *(float2*)&Mbuf[row*DD + 2*t] = make_float2(m0,m1);
        }
        __syncthreads();
        // ---- D (t<900): g = M @ pwi^T + pbi; 14 reg + 5 LDS + 19 streamed
        if (t < G3){
            const h8* W = pwiQ + t;
            const h8* Mc = (const h8*)M_h2;
            float a0=0.f, a1=0.f, a2=0.f, a3=0.f;
            dot4(wr0,  Mc[0],  a0,a1,a2,a3);
            dot4(wr1,  Mc[1],  a0,a1,a2,a3);
            dot4(wr2,  Mc[2],  a0,a1,a2,a3);
            dot4(wr3,  Mc[3],  a0,a1,a2,a3);
            dot4(wr4,  Mc[4],  a0,a1,a2,a3);
            dot4(wr5,  Mc[5],  a0,a1,a2,a3);
            dot4(wr6,  Mc[6],  a0,a1,a2,a3);
            dot4(wr7,  Mc[7],  a0,a1,a2,a3);
            dot4(wr8,  Mc[8],  a0,a1,a2,a3);
            dot4(wr9,  Mc[9],  a0,a1,a2,a3);
            dot4(wr10, Mc[10], a0,a1,a2,a3);
            dot4(wr11, Mc[11], a0,a1,a2,a3);
            dot4(wr12, Mc[12], a0,a1,a2,a3);
            dot4(wr13, Mc[13], a0,a1,a2,a3);
            dot4(Wlds[t],        Mc[NREG+0], a0,a1,a2,a3);
            dot4(Wlds[G3+t],     Mc[NREG+1], a0,a1,a2,a3);
            dot4(Wlds[2*G3+t],   Mc[NREG+2], a0,a1,a2,a3);
            dot4(Wlds[3*G3+t],   Mc[NREG+3], a0,a1,a2,a3);
            dot4(Wlds[4*G3+t],   Mc[NREG+4], a0,a1,a2,a3);
            #pragma unroll 4
            for (int c=NREG+NLDS;c<NC4;c++){
                h8 wv = W[(size_t)c*G3];
                dot4(wv, Mc[c], a0,a1,a2,a3);
            }
            g_s[t] = pbi_r + (a0+a2) + (a1+a3);
        }
        __syncthreads();
        // ---- E (t<150): GRU combine (pure LDS), write P row + pw
        if (t < PP){
            int d0 = 2*t, d1 = 2*t+1;
            float2 hv = *(const float2*)&hv_s[d0];
            float r0  = sigm(g_s[d0]      + ghp_s[d0]);
            float z0  = sigm(g_s[DD+d0]   + ghp_s[DD+d0]);
            float n0  = tanhf(g_s[2*DD+d0] + r0*ghp_s[2*DD+d0]);
            float p0  = (1.f-z0)*n0 + z0*hv.x;
            float r1  = sigm(g_s[d1]      + ghp_s[d1]);
            float z1  = sigm(g_s[DD+d1]   + ghp_s[DD+d1]);
            float n1  = tanhf(g_s[2*DD+d1] + r1*ghp_s[2*DD+d1]);
            float p1  = (1.f-z1)*n1 + z1*hv.y;
            *(float2*)&Hbuf[row*HDIM + pcol + d0] = make_float2(p0,p1);
            half2_t ph; ph.x = (_Float16)p0; ph.y = (_Float16)p1;
            P_h2[i][t] = ph;
            pw_s[d0] = p0*wk_r.x;
            pw_s[d1] = p1*wk_r.y;
        }
        __syncthreads();
    }
}

// ---------------- c-side elementwise combine ----------------
__global__ __launch_bounds__(320) void combine_c(
    const float* __restrict__ GIc, const float* __restrict__ GHc,
    const float* __restrict__ Mbuf, float* __restrict__ Hbuf, int clcol)
{
    size_t row = blockIdx.x;
    int d = threadIdx.x;
    if (d < DD){
        float ir = GIc[row*G3+d], iz = GIc[row*G3+DD+d], inn = GIc[row*G3+2*DD+d];
        float hr = GHc[row*G3+d], hz = GHc[row*G3+DD+d], hn  = GHc[row*G3+2*DD+d];
        float r  = sigm(ir+hr);
        float z  = sigm(iz+hz);
        float nn = tanhf(inn + r*hn);
        float h  = Mbuf[row*DD+d];
        Hbuf[row*HDIM + clcol + d] = (1.f-z)*nn + z*h;
    }
}

// ---------------- logits: out = x2 @ w2 + b2 (N=7) ----------------
__global__ __launch_bounds__(64) void logits_kernel(
    const float* __restrict__ x2, const float* __restrict__ w2,
    const float* __restrict__ b2, float* __restrict__ out)
{
    size_t row = blockIdx.x;
    int lane = threadIdx.x;
    float acc[7]={0,0,0,0,0,0,0};
    for (int d=lane; d<DD; d+=64){
        float x = x2[row*DD+d];
        #pragma unroll
        for (int c=0;c<7;c++) acc[c] += x*w2[d*7+c];
    }
    #pragma unroll
    for (int c=0;c<7;c++){
        float s = acc[c];
        #pragma unroll
        for (int o=32;o>0;o>>=1) s += __shfl_down(s,o);
        if (lane==0) out[row*7+c] = s + b2[c];
    }
}

extern "C" void kernel_launch(void* const* d_in, const int* in_sizes, int n_in,
                              void* d_out, int out_size, void* d_ws, size_t ws_size,
                              hipStream_t stream)
{
    const float* features = (const float*)d_in[0];
    const float* adj      = (const float*)d_in[1];
    const float* fc1_w    = (const float*)d_in[3];
    const float* fc1_b    = (const float*)d_in[4];
    const float* gc_wih   = (const float*)d_in[5];
    const float* gc_whh   = (const float*)d_in[6];
    const float* gc_bih   = (const float*)d_in[7];
    const float* gc_bhh   = (const float*)d_in[8];
    const float* gp_wih   = (const float*)d_in[9];
    const float* gp_whh   = (const float*)d_in[10];
    const float* gp_bih   = (const float*)d_in[11];
    const float* gp_bhh   = (const float*)d_in[12];
    const float* gat_wq   = (const float*)d_in[13];
    const float* gat_wk   = (const float*)d_in[14];
    const float* gat_b    = (const float*)d_in[15];
    const float* mlp_w0   = (const float*)d_in[16];
    const float* mlp_b0   = (const float*)d_in[17];
    const float* mlp_w1   = (const float*)d_in[18];
    const float* mlp_b1   = (const float*)d_in[19];
    const float* mlp_w2   = (const float*)d_in[20];
    const float* mlp_b2   = (const float*)d_in[21];
    float* out = (float*)d_out;

    float* ws = (float*)d_ws;
    size_t off = 0;
    float* Hbuf = ws + off; off += (size_t)ROWS*HDIM;
    float* bufA = ws + off; off += (size_t)ROWS*G3;    // GHp
    float* bufB = ws + off; off += (size_t)ROWS*G3;    // GIc / x1
    float* bufC = ws + off; off += (size_t)ROWS*G3;    // GHc / x2
    float* Mbuf = ws + off; off += (size_t)ROWS*DD;
    h8* pwiQ = (h8*)(ws + off); off += (size_t)LL*NC4*G3*4;
    h8* pwhQ = (h8*)(ws + off); off += (size_t)LL*NC4*G3*4;
    _Float16* gruF = (_Float16*)(ws + off); off += (size_t)12*G3*KP300/2;
    _Float16* fc1F = (_Float16*)(ws + off); off += (size_t)DD*EE/2;
    _Float16* mlp0F= (_Float16*)(ws + off); off += (size_t)DD*3728/2;
    _Float16* mlp1F= (_Float16*)(ws + off); off += (size_t)DD*KP300/2;
    (void)ws_size; (void)in_sizes; (void)n_in; (void)out_size;

    // 1. weight prep
    {
        pack_w_q<<<dim3((NC4*G3+255)/256, LL), 256, 0, stream>>>(gp_wih, pwiQ);
        pack_w_q<<<dim3((NC4*G3+255)/256, LL), 256, 0, stream>>>(gp_whh, pwhQ);
        conv_gru_w<<<dim3((G3*KP300+255)/256, 12), 256, 0, stream>>>(gp_whh, gc_wih, gc_whh, gruF);
        convT<<<(DD*EE+255)/256, 256, 0, stream>>>(fc1_w, fc1F, EE, DD, EE);
        convT<<<(DD*3728+255)/256, 256, 0, stream>>>(mlp_w0, mlp0F, HDIM, DD, 3728);
        convT<<<(DD*KP300+255)/256, 256, 0, stream>>>(mlp_w1, mlp1F, DD, DD, KP300);
    }
    // 2. H0 = relu(features @ fc1_w + fc1_b) -> Hbuf col 0
    gemm_mfma<<<dim3(5,36),256,0,stream>>>(features, EE, fc1F, EE, fc1_b,
                                           Hbuf, HDIM, DD, EE, 1);
    // 3. features -> Hbuf cols [2700,3724)
    featcopy<<<ROWS,256,0,stream>>>(features, Hbuf);

    for (int l=0;l<LL;l++){
        int ccol  = (l==0)? 0 : 300 + (l-1)*600;
        int hcol  = l*300;
        int pcol  = 600 + l*600;
        int clcol = 300 + l*600;
        const h8* pwiQl = pwiQ + (size_t)l*NC4*G3;
        const h8* pwhQl = pwhQ + (size_t)l*NC4*G3;
        const _Float16* pwhF = gruF + (size_t)(l*3+0)*G3*KP300;
        const _Float16* cwiF = gruF + (size_t)(l*3+1)*G3*KP300;
        const _Float16* cwhF = gruF + (size_t)(l*3+2)*G3*KP300;

        // GHp = Hin @ pwh^T + pbh
        gemm_mfma<<<dim3(15,36),256,0,stream>>>(Hbuf+hcol, HDIM, pwhF, KP300,
                                                gp_bhh + l*G3, bufA, G3, G3, DD, 0);
        // fused: scan (blocks 0..47) + GIc GEMM (blocks 48..587)
        scan_kernel<<<BB+GIC_TILES,1024,0,stream>>>(Hbuf, bufA, pwiQl, pwhQl,
                                          gp_bih + l*G3, gp_bhh + l*G3,
                                          gat_wk + l*DD, gat_wq + l*DD, gat_b, l,
                                          adj, Mbuf, ccol, hcol, pcol,
                                          cwiF, gc_bih + l*G3, bufB);
        // GHc = M @ cwh^T + cbh
        gemm_mfma<<<dim3(15,36),256,0,stream>>>(Mbuf, DD, cwhF, KP300,
                                                gc_bhh + l*G3, bufC, G3, G3, DD, 0);
        // CL = GRU-combine
        combine_c<<<ROWS,320,0,stream>>>(bufB, bufC, Mbuf, Hbuf, clcol);
    }

    // MLP
    gemm_mfma<<<dim3(5,36),256,0,stream>>>(Hbuf, HDIM, mlp0F, 3728, mlp_b0,
                                           bufB, DD, DD, HDIM, 1);
    gemm_mfma<<<dim3(5,36),256,0,stream>>>(bufB, DD, mlp1F, KP300, mlp_b1,
                                           bufC, DD, DD, DD, 1);
    logits_kernel<<<ROWS,64,0,stream>>>(bufC, mlp_w2, mlp_b2, out);
}